// Round 6
// baseline (442.255 us; speedup 1.0000x reference)
//
#include <hip/hip_runtime.h>

// Problem dims (fixed by setup_inputs)
#define B_   64
#define C_   256
#define T_   1024
#define H_   512
#define G_   192   // 64 tx groups + 128 rx groups (b*2+i)

// d_out layout (reference return order, flattened)
#define OUT_DIST 0
#define OUT_AZI  (64*512)
#define OUT_ELE  (2*64*512)
#define OUT_RX   (3*64*512)
#define OUT_SP   (3*64*512 + 64*2*256*1024)

typedef _Float16 half8  __attribute__((ext_vector_type(8)));
typedef _Float16 half4v __attribute__((ext_vector_type(4)));
typedef float    floatx4 __attribute__((ext_vector_type(4)));

// ---------------------------------------------------------------------------
// Split W into two f16 terms: w16 layout [tx_hi | tx_lo | rx_hi | rx_lo],
// each 256x256 halfs row-major [o][c]. W = hi + lo to ~22 mantissa bits.
__global__ __launch_bounds__(256) void split_w(
    const float* __restrict__ Wtx, const float* __restrict__ Wrx,
    _Float16* __restrict__ w16)
{
    int e = blockIdx.x * 256 + threadIdx.x;      // [0, 131072)
    int m = e >> 16;                              // 0: tx, 1: rx
    int i = e & 65535;
    float v = m ? Wrx[i] : Wtx[i];
    _Float16 hi = (_Float16)v;
    _Float16 lo = (_Float16)(v - (float)hi);
    w16[(size_t)m * 131072 + i] = hi;
    w16[(size_t)m * 131072 + 65536 + i] = lo;
}

// ---------------------------------------------------------------------------
// Fused f16-split MFMA GEMM + LIF scan, v3: deep-issue staging + cross-phase
// software pipelining.
// Block = (g, 64-wide o-tile), 256 threads (4 waves); g = bx%192 (same-g
// blocks 192 apart -> same XCD slot pattern, L2/L3 reuse of Sg).
// Pipeline per t-tile: [pre holds half0 loads] cvt->S16 | issue half1 loads |
// MFMA h0 | cvt->S16 | issue next-tile h0 loads | MFMA h1 | epi->Mlds |
// wave0 scan | rx spike-tile write. S16/Mlds alias (34,816 B), barriers
// separate phases; prefetch registers are thread-private so they safely
// stay in flight across barriers.
__global__ __launch_bounds__(256, 3) void lif_mfma_v3(
    const float* __restrict__ transmit, const float* __restrict__ receive,
    const float* __restrict__ btx, const float* __restrict__ brx,
    const _Float16* __restrict__ w16, float* __restrict__ out,
    float* __restrict__ txCnt)
{
    __shared__ __align__(16) float ldsraw[8704];   // 34,816 B
    float*     Mlds = ldsraw;                      // [128 t][68 f32]
    _Float16*  S16  = (_Float16*)ldsraw;           // [128 t][136 halfs]

    const int tid = threadIdx.x;
    const int ot  = blockIdx.x / G_;     // 0..3
    const int g   = blockIdx.x % G_;     // 0..191
    const int o0  = ot * 64;
    const bool isRx = (g >= 64);
    const int gr  = g - 64;

    const float* Sg = isRx ? (receive + (size_t)gr * C_ * T_)
                           : (transmit + (size_t)g * C_ * T_);
    const _Float16* whi = w16 + (isRx ? 131072 : 0);
    const _Float16* wlo = whi + 65536;
    const float* bp = isRx ? brx : btx;

    const int lane = tid & 63;
    const int wv   = tid >> 6;           // wave -> o-strip wv*16
    const int col  = lane & 15;
    const int quad = lane >> 4;          // 0..3

    // A-fragments (W hi/lo) for this wave's o-strip, all K.
    const int oA = o0 + wv * 16 + col;
    half8 Ahi[8], Alo[8];
#pragma unroll
    for (int ck = 0; ck < 8; ++ck) {
        Ahi[ck] = *(const half8*)(whi + (size_t)oA * 256 + ck * 32 + quad * 8);
        Alo[ck] = *(const half8*)(wlo + (size_t)oA * 256 + ck * 32 + quad * 8);
    }
    floatx4 bias4 = *(const floatx4*)(bp + o0 + wv * 16 + quad * 4);

    // Staging mapping: c-rows cq*4..+4 (cq=tid&31), t-run tq*16..+16 (tq=tid>>5).
    const int cq = tid & 31;
    const int tq = tid >> 5;

    float mem = 0.f, spk = 0.f, cnt = 0.f;

    // Burst-issue prefetch for tile 0, half 0: 16 independent 16B loads.
    floatx4 pre[16];
    {
        const float* sb = Sg + (size_t)(cq * 4) * T_ + tq * 16;
#pragma unroll
        for (int i = 0; i < 4; ++i)
#pragma unroll
            for (int q = 0; q < 4; ++q)
                pre[i * 4 + q] = *(const floatx4*)(sb + (size_t)i * T_ + q * 4);
    }

    for (int tt = 0; tt < 8; ++tt) {
        const int t0 = tt * 128;

        floatx4 acc[8];
#pragma unroll
        for (int nt = 0; nt < 8; ++nt) acc[nt] = bias4;

        // ================= half 0 =================
        __syncthreads();   // S16/Mlds free (prev tile fully consumed)
        // cvt + transposed f16 store of half0 (consumes pre)
#pragma unroll
        for (int j = 0; j < 16; ++j) {
            int q = j >> 2, r = j & 3;
            half4v h = { (_Float16)pre[q][r],      (_Float16)pre[4 + q][r],
                         (_Float16)pre[8 + q][r],  (_Float16)pre[12 + q][r] };
            *(half4v*)(S16 + (size_t)(tq * 16 + j) * 136 + cq * 4) = h;
        }
        __syncthreads();

        // issue half1 loads (in flight across the MFMA phase)
        {
            const float* sb = Sg + (size_t)(128 + cq * 4) * T_ + t0 + tq * 16;
#pragma unroll
            for (int i = 0; i < 4; ++i)
#pragma unroll
                for (int q = 0; q < 4; ++q)
                    pre[i * 4 + q] = *(const floatx4*)(sb + (size_t)i * T_ + q * 4);
        }

        // MFMA over half0's 4 K-chunks
#pragma unroll
        for (int ckl = 0; ckl < 4; ++ckl) {
#pragma unroll
            for (int nt = 0; nt < 8; ++nt) {
                half8 bf = *(const half8*)(S16 + (size_t)(nt * 16 + col) * 136
                                           + ckl * 32 + quad * 8);
                acc[nt] = __builtin_amdgcn_mfma_f32_16x16x32_f16(
                    Ahi[ckl], bf, acc[nt], 0, 0, 0);
                acc[nt] = __builtin_amdgcn_mfma_f32_16x16x32_f16(
                    Alo[ckl], bf, acc[nt], 0, 0, 0);
            }
        }
        __syncthreads();   // all waves done reading S16 half0

        // ================= half 1 =================
#pragma unroll
        for (int j = 0; j < 16; ++j) {
            int q = j >> 2, r = j & 3;
            half4v h = { (_Float16)pre[q][r],      (_Float16)pre[4 + q][r],
                         (_Float16)pre[8 + q][r],  (_Float16)pre[12 + q][r] };
            *(half4v*)(S16 + (size_t)(tq * 16 + j) * 136 + cq * 4) = h;
        }
        __syncthreads();

        // issue next tile's half0 loads (covered by MFMA+epi+scan+write)
        if (tt < 7) {
            const float* sb = Sg + (size_t)(cq * 4) * T_ + (t0 + 128) + tq * 16;
#pragma unroll
            for (int i = 0; i < 4; ++i)
#pragma unroll
                for (int q = 0; q < 4; ++q)
                    pre[i * 4 + q] = *(const floatx4*)(sb + (size_t)i * T_ + q * 4);
        }

#pragma unroll
        for (int ckl = 0; ckl < 4; ++ckl) {
#pragma unroll
            for (int nt = 0; nt < 8; ++nt) {
                half8 bf = *(const half8*)(S16 + (size_t)(nt * 16 + col) * 136
                                           + ckl * 32 + quad * 8);
                acc[nt] = __builtin_amdgcn_mfma_f32_16x16x32_f16(
                    Ahi[4 + ckl], bf, acc[nt], 0, 0, 0);
                acc[nt] = __builtin_amdgcn_mfma_f32_16x16x32_f16(
                    Alo[4 + ckl], bf, acc[nt], 0, 0, 0);
            }
        }
        __syncthreads();   // MFMA done reading S16 before Mlds overwrite

        // ---- epilogue: D-frag -> Mlds[t][o]; t = nt*16+col, o = wv*16+quad*4+r
#pragma unroll
        for (int nt = 0; nt < 8; ++nt) {
            int t = nt * 16 + col;
            *(floatx4*)(Mlds + (size_t)t * 68 + wv * 16 + quad * 4) = acc[nt];
        }
        __syncthreads();

        // ---- LIF scan: wave0, lane = o; 128 sequential steps ----
        if (tid < 64) {
            if (isRx) {
#pragma unroll 8
                for (int t = 0; t < 128; ++t) {
                    float x = Mlds[t * 68 + tid];
                    mem = 0.9f * mem + x - spk * 0.75f;
                    spk = (mem > 0.75f) ? 1.0f : 0.0f;
                    cnt += spk;
                    Mlds[t * 68 + tid] = spk;
                }
            } else {
#pragma unroll 8
                for (int t = 0; t < 128; ++t) {
                    float x = Mlds[t * 68 + tid];
                    mem = 0.9f * mem + x - spk * 0.75f;
                    spk = (mem > 0.75f) ? 1.0f : 0.0f;
                    cnt += spk;
                }
            }
        }
        __syncthreads();

        // ---- rx: spike tile [64 o][128 t] transposed coalesced write ----
        if (isRx) {
            float* dstb = out + (size_t)OUT_RX + (size_t)gr * C_ * T_
                          + (size_t)o0 * T_ + t0;
            const int m = tid & 7;
            const int or0 = tid >> 3;    // 0..31
#pragma unroll
            for (int p = 0; p < 2; ++p) {
                int orow = or0 + p * 32;
                float* drow = dstb + (size_t)orow * T_;
#pragma unroll
                for (int q = 0; q < 4; ++q) {
                    int tq2 = m * 4 + q * 32;
                    float4 v = make_float4(Mlds[(tq2 + 0) * 68 + orow],
                                           Mlds[(tq2 + 1) * 68 + orow],
                                           Mlds[(tq2 + 2) * 68 + orow],
                                           Mlds[(tq2 + 3) * 68 + orow]);
                    *(float4*)(drow + tq2) = v;
                }
            }
        }
        // loop-top barrier protects Mlds until next tile's staging store
    }

    if (tid < 64) {
        if (isRx) out[(size_t)OUT_SP + (size_t)gr * 256 + o0 + tid] = cnt;
        else      txCnt[(size_t)g * 256 + o0 + tid] = cnt;
    }
}

// ---------------------------------------------------------------------------
// Fallback (tiny ws): round-1 fused fp32 kernel. Needs 64 KB ws.
__global__ __launch_bounds__(128) void lif_gemm_scan(
    const float* __restrict__ transmit, const float* __restrict__ receive,
    const float* __restrict__ Wtx, const float* __restrict__ btx,
    const float* __restrict__ Wrx, const float* __restrict__ brx,
    float* __restrict__ out, float* __restrict__ wsF)
{
    __shared__ float lds[128 * 68];
    float* Slds = lds;
    float* Wlds = lds + 4096;
    float* Mlds = lds;

    const int tid = threadIdx.x;
    const int bx  = blockIdx.x;
    const int ot  = bx / G_;
    const int g   = bx % G_;
    const int o0  = ot * 64;
    const bool isRx = (g >= 64);

    const float* Sg = isRx ? (receive + (size_t)(g - 64) * C_ * T_)
                           : (transmit + (size_t)g * C_ * T_);
    const float* Wp = isRx ? Wrx : Wtx;
    const float* bp = isRx ? brx : btx;

    const int ti = tid & 15;
    const int oi = tid >> 4;
    const int tb = ti * 4;
    const int ob = oi * 4;

    float bias[2][4];
#pragma unroll
    for (int os = 0; os < 2; ++os)
#pragma unroll
        for (int j = 0; j < 4; ++j)
            bias[os][j] = bp[o0 + os * 32 + ob + j];

    float mem = 0.f, spk = 0.f, cnt = 0.f;

    for (int tt = 0; tt < 8; ++tt) {
        const int t0 = tt * 128;
        float acc[8][8];
#pragma unroll
        for (int ii = 0; ii < 8; ++ii)
#pragma unroll
            for (int jj = 0; jj < 8; ++jj)
                acc[ii][jj] = bias[jj >> 2][jj & 3];

        for (int kk = 0; kk < 8; ++kk) {
            const int c0 = kk * 32;
#pragma unroll
            for (int p = 0; p < 8; ++p) {
                int idx = tid + p * 128;
                int c = idx >> 5, t4 = idx & 31;
                *(float4*)(Slds + c * 128 + t4 * 4) =
                    *(const float4*)(Sg + (size_t)(c0 + c) * T_ + t0 + t4 * 4);
            }
#pragma unroll
            for (int p = 0; p < 4; ++p) {
                int idx = tid + p * 128;
                int o = idx >> 3, c4 = idx & 7;
                float4 w = *(const float4*)(Wp + (size_t)(o0 + o) * C_ + c0 + c4 * 4);
                Wlds[(c4 * 4 + 0) * 64 + o] = w.x;
                Wlds[(c4 * 4 + 1) * 64 + o] = w.y;
                Wlds[(c4 * 4 + 2) * 64 + o] = w.z;
                Wlds[(c4 * 4 + 3) * 64 + o] = w.w;
            }
            __syncthreads();
#pragma unroll 8
            for (int k = 0; k < 32; ++k) {
                float4 a0 = *(const float4*)(Slds + k * 128 + tb);
                float4 a1 = *(const float4*)(Slds + k * 128 + 64 + tb);
                float4 b0 = *(const float4*)(Wlds + k * 64 + ob);
                float4 b1 = *(const float4*)(Wlds + k * 64 + 32 + ob);
                float a[8]  = {a0.x, a0.y, a0.z, a0.w, a1.x, a1.y, a1.z, a1.w};
                float bv[8] = {b0.x, b0.y, b0.z, b0.w, b1.x, b1.y, b1.z, b1.w};
#pragma unroll
                for (int ii = 0; ii < 8; ++ii)
#pragma unroll
                    for (int jj = 0; jj < 8; ++jj)
                        acc[ii][jj] += a[ii] * bv[jj];
            }
            __syncthreads();
        }

#pragma unroll
        for (int ii = 0; ii < 8; ++ii) {
            int t = (ii >> 2) * 64 + tb + (ii & 3);
#pragma unroll
            for (int os = 0; os < 2; ++os) {
                float4 v = make_float4(acc[ii][os * 4 + 0], acc[ii][os * 4 + 1],
                                       acc[ii][os * 4 + 2], acc[ii][os * 4 + 3]);
                *(float4*)(Mlds + t * 68 + os * 32 + ob) = v;
            }
        }
        __syncthreads();

        if (tid < 64) {
#pragma unroll 4
            for (int t = 0; t < 128; ++t) {
                float x = Mlds[t * 68 + tid];
                mem = 0.9f * mem + x - spk * 0.75f;
                spk = (mem > 0.75f) ? 1.0f : 0.0f;
                cnt += spk;
                Mlds[t * 68 + tid] = spk;
            }
        }
        __syncthreads();

        if (isRx) {
            float* dst = out + (size_t)OUT_RX + (size_t)(g - 64) * C_ * T_
                         + (size_t)o0 * T_ + t0;
            int m = tid & 7;
            int orow0 = tid >> 3;
#pragma unroll
            for (int p = 0; p < 4; ++p) {
                int orow = orow0 + p * 16;
#pragma unroll
                for (int q = 0; q < 4; ++q) {
                    int tq = m * 4 + q * 32;
                    float4 v = make_float4(Mlds[(tq + 0) * 68 + orow],
                                           Mlds[(tq + 1) * 68 + orow],
                                           Mlds[(tq + 2) * 68 + orow],
                                           Mlds[(tq + 3) * 68 + orow]);
                    *(float4*)(dst + (size_t)orow * T_ + tq) = v;
                }
            }
        }
        __syncthreads();
    }

    if (tid < 64) {
        if (isRx) out[(size_t)OUT_SP + (size_t)(g - 64) * C_ + o0 + tid] = cnt;
        else      wsF[(size_t)g * C_ + o0 + tid] = cnt;
    }
}

// Heads: layernorm over C=256 + GEMV to H=512, 3 heads x 64 batches
__global__ __launch_bounds__(256) void heads_kernel(
    const float* __restrict__ wsF, const float* __restrict__ sp,
    const float* __restrict__ Wd, const float* __restrict__ bd,
    const float* __restrict__ Wa, const float* __restrict__ ba,
    const float* __restrict__ We, const float* __restrict__ be,
    const float* __restrict__ gd, const float* __restrict__ ga, const float* __restrict__ ge,
    const float* __restrict__ based, const float* __restrict__ basea, const float* __restrict__ basee,
    float* __restrict__ out)
{
    __shared__ float fv[256];
    __shared__ float red[8];
    const int tid = threadIdx.x;
    const int hd  = blockIdx.x >> 6;
    const int b   = blockIdx.x & 63;

    float f;
    if (hd == 0) {
        f = wsF[b * 256 + tid] * (1.f / 1024.f);
    } else {
        float l = sp[(2 * b) * 256 + tid];
        float r = sp[(2 * b + 1) * 256 + tid];
        f = ((hd == 1) ? (l - r) : (l + r)) * (1.f / 1024.f);
    }

    float v = f;
#pragma unroll
    for (int off = 32; off > 0; off >>= 1) v += __shfl_down(v, off, 64);
    if ((tid & 63) == 0) red[tid >> 6] = v;
    __syncthreads();
    float mu = (red[0] + red[1] + red[2] + red[3]) * (1.f / 256.f);

    float d = f - mu;
    v = d * d;
#pragma unroll
    for (int off = 32; off > 0; off >>= 1) v += __shfl_down(v, off, 64);
    if ((tid & 63) == 0) red[4 + (tid >> 6)] = v;
    __syncthreads();
    float var  = (red[4] + red[5] + red[6] + red[7]) * (1.f / 256.f);
    float rstd = rsqrtf(var + 1e-5f);
    fv[tid] = d * rstd;
    __syncthreads();

    const float* W    = (hd == 0) ? Wd : (hd == 1) ? Wa : We;
    const float* bb   = (hd == 0) ? bd : (hd == 1) ? ba : be;
    const float* base = (hd == 0) ? based : (hd == 1) ? basea : basee;
    float gain = (hd == 0) ? gd[0] : (hd == 1) ? ga[0] : ge[0];
    float s = 0.3f / (1.f + expf(-gain));

    const float4* fv4 = (const float4*)fv;
#pragma unroll
    for (int hh = 0; hh < 2; ++hh) {
        int h = tid + hh * 256;
        const float4* W4 = (const float4*)(W + (size_t)h * 256);
        float acc = 0.f;
#pragma unroll 8
        for (int c = 0; c < 64; ++c) {
            float4 w = W4[c];
            float4 x = fv4[c];
            acc += w.x * x.x + w.y * x.y + w.z * x.z + w.w * x.w;
        }
        float r = acc + bb[h];
        float o = base[b * 512 + h] + s * r;
        out[(size_t)hd * (64 * 512) + b * 512 + h] = fmaxf(o, 0.f);
    }
}

extern "C" void kernel_launch(void* const* d_in, const int* in_sizes, int n_in,
                              void* d_out, int out_size, void* d_ws, size_t ws_size,
                              hipStream_t stream)
{
    const float* transmit = (const float*)d_in[0];
    const float* receive  = (const float*)d_in[1];
    const float* based    = (const float*)d_in[2];
    const float* basea    = (const float*)d_in[3];
    const float* basee    = (const float*)d_in[4];
    const float* Wtx      = (const float*)d_in[5];
    const float* btx      = (const float*)d_in[6];
    const float* Wrx      = (const float*)d_in[7];
    const float* brx      = (const float*)d_in[8];
    const float* Wd       = (const float*)d_in[9];
    const float* bd       = (const float*)d_in[10];
    const float* Wa       = (const float*)d_in[11];
    const float* ba       = (const float*)d_in[12];
    const float* We       = (const float*)d_in[13];
    const float* be       = (const float*)d_in[14];
    const float* gd       = (const float*)d_in[15];
    const float* ga       = (const float*)d_in[16];
    const float* ge       = (const float*)d_in[17];
    float* out = (float*)d_out;
    float* spOut = out + (size_t)OUT_SP;

    const size_t need = 512 * 1024 + 64 * 1024;   // W16 splits + tx counts

    if (ws_size >= need) {
        _Float16* w16   = (_Float16*)d_ws;
        float*    txCnt = (float*)d_ws + 131072;  // after 512 KB

        hipLaunchKernelGGL(split_w, dim3(512), dim3(256), 0, stream,
                           Wtx, Wrx, w16);
        hipLaunchKernelGGL(lif_mfma_v3, dim3(768), dim3(256), 0, stream,
                           transmit, receive, btx, brx, w16, out, txCnt);
        hipLaunchKernelGGL(heads_kernel, dim3(192), dim3(256), 0, stream,
                           txCnt, spOut, Wd, bd, Wa, ba, We, be,
                           gd, ga, ge, based, basea, basee, out);
    } else {
        float* wsF = (float*)d_ws;
        hipLaunchKernelGGL(lif_gemm_scan, dim3(768), dim3(128), 0, stream,
                           transmit, receive, Wtx, btx, Wrx, brx, out, wsF);
        hipLaunchKernelGGL(heads_kernel, dim3(192), dim3(256), 0, stream,
                           wsF, spOut, Wd, bd, Wa, ba, We, be,
                           gd, ga, ge, based, basea, basee, out);
    }
}

// Round 7
// 379.244 us; speedup vs baseline: 1.1661x; 1.1661x over previous
//
#include <hip/hip_runtime.h>

// Problem dims (fixed by setup_inputs)
#define B_   64
#define C_   256
#define T_   1024
#define H_   512
#define G_   192   // 64 tx groups + 128 rx groups (b*2+i)

// d_out layout (reference return order, flattened)
#define OUT_DIST 0
#define OUT_AZI  (64*512)
#define OUT_ELE  (2*64*512)
#define OUT_RX   (3*64*512)
#define OUT_SP   (3*64*512 + 64*2*256*1024)

typedef _Float16 half8  __attribute__((ext_vector_type(8)));
typedef float    floatx4 __attribute__((ext_vector_type(4)));

// ---------------------------------------------------------------------------
// Split W into two f16 terms: w16 layout [tx_hi | tx_lo | rx_hi | rx_lo],
// each 256x256 halfs row-major [o][c]. W = hi + lo to ~22 mantissa bits.
__global__ __launch_bounds__(256) void split_w(
    const float* __restrict__ Wtx, const float* __restrict__ Wrx,
    _Float16* __restrict__ w16)
{
    int e = blockIdx.x * 256 + threadIdx.x;      // [0, 131072)
    int m = e >> 16;                              // 0: tx, 1: rx
    int i = e & 65535;
    float v = m ? Wrx[i] : Wtx[i];
    _Float16 hi = (_Float16)v;
    _Float16 lo = (_Float16)(v - (float)hi);
    w16[(size_t)m * 131072 + i] = hi;
    w16[(size_t)m * 131072 + 65536 + i] = lo;
}

// ---------------------------------------------------------------------------
// Fused f16-split MFMA GEMM + LIF scan, v4: LDS double-buffered K-quarters,
// loads issued inside the MFMA phase (no cross-barrier register residency ->
// no spill), epilogue split into two 64-t halves aliased on the free buffer,
// scan distributed across all 4 waves (16 lanes each).
// Block = (g, 64-o tile), 256 threads; g = bx%192 (same-g blocks co-resident
// on one XCD for L2 reuse of Sg).
__global__ __launch_bounds__(256, 3) void lif_mfma_v4(
    const float* __restrict__ transmit, const float* __restrict__ receive,
    const float* __restrict__ btx, const float* __restrict__ brx,
    const _Float16* __restrict__ w16, float* __restrict__ out,
    float* __restrict__ txCnt)
{
    // Two K-quarter buffers [128 t][72 halfs] (18,432 B each).
    __shared__ __align__(16) _Float16 s16[2 * 9216];
    _Float16* bufA = s16;
    _Float16* bufB = s16 + 9216;
    float*    E    = (float*)bufB;   // epilogue [64 t][68 f32], aliases bufB

    const int tid = threadIdx.x;
    const int ot  = blockIdx.x / G_;     // 0..3
    const int g   = blockIdx.x % G_;     // 0..191
    const int o0  = ot * 64;
    const bool isRx = (g >= 64);
    const int gr  = g - 64;

    const float* Sg = isRx ? (receive + (size_t)gr * C_ * T_)
                           : (transmit + (size_t)g * C_ * T_);
    const _Float16* whi = w16 + (isRx ? 131072 : 0);
    const _Float16* wlo = whi + 65536;
    const float* bp = isRx ? brx : btx;

    const int lane = tid & 63;
    const int wv   = tid >> 6;           // wave -> o-strip wv*16
    const int col  = lane & 15;
    const int quad = lane >> 4;          // 0..3

    // A-fragments (W hi/lo) for this wave's o-strip, all 8 K-chunks of 32c.
    const int oA = o0 + wv * 16 + col;
    half8 Ahi[8], Alo[8];
#pragma unroll
    for (int ck = 0; ck < 8; ++ck) {
        Ahi[ck] = *(const half8*)(whi + (size_t)oA * 256 + ck * 32 + quad * 8);
        Alo[ck] = *(const half8*)(wlo + (size_t)oA * 256 + ck * 32 + quad * 8);
    }
    floatx4 bias4 = *(const floatx4*)(bp + o0 + wv * 16 + quad * 4);

    // Staging mapping: tq = t-chunk of 4 (0..31), cq = c-group of 8 (0..7).
    const int tq = tid & 31;
    const int cq = tid >> 5;

    // LIF carry for scanning lanes ((tid&63)<16): o = wv*16 + (tid&15).
    float mem = 0.f, spk = 0.f, cnt = 0.f;

    // Prologue: stage quarter 0 of tile 0 into bufA.
    {
        const float* sb = Sg + (size_t)(cq * 8) * T_ + tq * 4;
        floatx4 va[8];
#pragma unroll
        for (int i = 0; i < 8; ++i)
            va[i] = *(const floatx4*)(sb + (size_t)i * T_);
#pragma unroll
        for (int j = 0; j < 4; ++j) {
            half8 hv = { (_Float16)va[0][j], (_Float16)va[1][j],
                         (_Float16)va[2][j], (_Float16)va[3][j],
                         (_Float16)va[4][j], (_Float16)va[5][j],
                         (_Float16)va[6][j], (_Float16)va[7][j] };
            *(half8*)(bufA + (size_t)(tq * 4 + j) * 72 + cq * 8) = hv;
        }
        __syncthreads();
    }

    for (int tt = 0; tt < 8; ++tt) {
        floatx4 acc[8];
#pragma unroll
        for (int nt = 0; nt < 8; ++nt) acc[nt] = bias4;

        // ---- 4 K-quarter phases; buffers rotate; loads overlap MFMA ----
#pragma unroll
        for (int qt = 0; qt < 4; ++qt) {
            const _Float16* src = (qt & 1) ? bufB : bufA;
            _Float16*       dst = (qt & 1) ? bufA : bufB;

            const bool have = !(tt == 7 && qt == 3);
            const int nqt = (qt + 1) & 3;
            const int ntt = tt + (qt == 3 ? 1 : 0);

            // Issue next quarter's loads (consumed after MFMA, same phase).
            floatx4 va[8];
            if (have) {
                const float* sb = Sg + (size_t)(nqt * 64 + cq * 8) * T_
                                  + ntt * 128 + tq * 4;
#pragma unroll
                for (int i = 0; i < 8; ++i)
                    va[i] = *(const floatx4*)(sb + (size_t)i * T_);
            }

            // MFMA this quarter's 2 chunks (loads in flight meanwhile).
#pragma unroll
            for (int ck2 = 0; ck2 < 2; ++ck2) {
                const int ck = qt * 2 + ck2;
#pragma unroll
                for (int nt = 0; nt < 8; ++nt) {
                    half8 bf = *(const half8*)(src + (size_t)(nt * 16 + col) * 72
                                               + ck2 * 32 + quad * 8);
                    acc[nt] = __builtin_amdgcn_mfma_f32_16x16x32_f16(
                        Ahi[ck], bf, acc[nt], 0, 0, 0);
                    acc[nt] = __builtin_amdgcn_mfma_f32_16x16x32_f16(
                        Alo[ck], bf, acc[nt], 0, 0, 0);
                }
            }

            // Convert+store next quarter into the other buffer.
            if (have) {
#pragma unroll
                for (int j = 0; j < 4; ++j) {
                    half8 hv = { (_Float16)va[0][j], (_Float16)va[1][j],
                                 (_Float16)va[2][j], (_Float16)va[3][j],
                                 (_Float16)va[4][j], (_Float16)va[5][j],
                                 (_Float16)va[6][j], (_Float16)va[7][j] };
                    *(half8*)(dst + (size_t)(tq * 4 + j) * 72 + cq * 8) = hv;
                }
            }
            __syncthreads();
        }

        // ---- epilogue in two 64-t halves on E (= bufB, free after qt=3) ----
#pragma unroll
        for (int h = 0; h < 2; ++h) {
            // acc -> E[tl][o]; rows tl = (nt-h*4)*16+col, o = wv*16+quad*4+r
#pragma unroll
            for (int ntl = 0; ntl < 4; ++ntl) {
                int tl = ntl * 16 + col;
                *(floatx4*)(E + (size_t)tl * 68 + wv * 16 + quad * 4) =
                    acc[h * 4 + ntl];
            }
            __syncthreads();

            // scan 64 steps; each wave's lanes 0..15 own o = wv*16 + lane.
            if ((tid & 63) < 16) {
                const int oloc = wv * 16 + (tid & 15);
                if (isRx) {
#pragma unroll 8
                    for (int t = 0; t < 64; ++t) {
                        float x = E[t * 68 + oloc];
                        mem = 0.9f * mem + x - spk * 0.75f;
                        spk = (mem > 0.75f) ? 1.0f : 0.0f;
                        cnt += spk;
                        E[t * 68 + oloc] = spk;
                    }
                } else {
#pragma unroll 8
                    for (int t = 0; t < 64; ++t) {
                        float x = E[t * 68 + oloc];
                        mem = 0.9f * mem + x - spk * 0.75f;
                        spk = (mem > 0.75f) ? 1.0f : 0.0f;
                        cnt += spk;
                    }
                }
            }
            __syncthreads();

            // rx: write spike half-tile [64 o][64 t], transposed, 64B runs.
            if (isRx) {
                const int olane = tid >> 2;          // 0..63
                const int tl4   = (tid & 3) * 4;     // 0,4,8,12
                float* drow = out + (size_t)OUT_RX + (size_t)gr * C_ * T_
                              + (size_t)(o0 + olane) * T_ + tt * 128 + h * 64;
#pragma unroll
                for (int q = 0; q < 4; ++q) {
                    int t = tl4 + q * 16;
                    float4 v = make_float4(E[(t + 0) * 68 + olane],
                                           E[(t + 1) * 68 + olane],
                                           E[(t + 2) * 68 + olane],
                                           E[(t + 3) * 68 + olane]);
                    *(float4*)(drow + t) = v;
                }
            }
            __syncthreads();   // E free for next half / next tile's staging
        }
    }

    // spike-count outputs (scanning lanes hold the carries)
    if ((tid & 63) < 16) {
        const int og = o0 + wv * 16 + (tid & 15);
        if (isRx) out[(size_t)OUT_SP + (size_t)gr * 256 + og] = cnt;
        else      txCnt[(size_t)g * 256 + og] = cnt;
    }
}

// ---------------------------------------------------------------------------
// Fallback (tiny ws): round-1 fused fp32 kernel. Needs 64 KB ws.
__global__ __launch_bounds__(128) void lif_gemm_scan(
    const float* __restrict__ transmit, const float* __restrict__ receive,
    const float* __restrict__ Wtx, const float* __restrict__ btx,
    const float* __restrict__ Wrx, const float* __restrict__ brx,
    float* __restrict__ out, float* __restrict__ wsF)
{
    __shared__ float lds[128 * 68];
    float* Slds = lds;
    float* Wlds = lds + 4096;
    float* Mlds = lds;

    const int tid = threadIdx.x;
    const int bx  = blockIdx.x;
    const int ot  = bx / G_;
    const int g   = bx % G_;
    const int o0  = ot * 64;
    const bool isRx = (g >= 64);

    const float* Sg = isRx ? (receive + (size_t)(g - 64) * C_ * T_)
                           : (transmit + (size_t)g * C_ * T_);
    const float* Wp = isRx ? Wrx : Wtx;
    const float* bp = isRx ? brx : btx;

    const int ti = tid & 15;
    const int oi = tid >> 4;
    const int tb = ti * 4;
    const int ob = oi * 4;

    float bias[2][4];
#pragma unroll
    for (int os = 0; os < 2; ++os)
#pragma unroll
        for (int j = 0; j < 4; ++j)
            bias[os][j] = bp[o0 + os * 32 + ob + j];

    float mem = 0.f, spk = 0.f, cnt = 0.f;

    for (int tt = 0; tt < 8; ++tt) {
        const int t0 = tt * 128;
        float acc[8][8];
#pragma unroll
        for (int ii = 0; ii < 8; ++ii)
#pragma unroll
            for (int jj = 0; jj < 8; ++jj)
                acc[ii][jj] = bias[jj >> 2][jj & 3];

        for (int kk = 0; kk < 8; ++kk) {
            const int c0 = kk * 32;
#pragma unroll
            for (int p = 0; p < 8; ++p) {
                int idx = tid + p * 128;
                int c = idx >> 5, t4 = idx & 31;
                *(float4*)(Slds + c * 128 + t4 * 4) =
                    *(const float4*)(Sg + (size_t)(c0 + c) * T_ + t0 + t4 * 4);
            }
#pragma unroll
            for (int p = 0; p < 4; ++p) {
                int idx = tid + p * 128;
                int o = idx >> 3, c4 = idx & 7;
                float4 w = *(const float4*)(Wp + (size_t)(o0 + o) * C_ + c0 + c4 * 4);
                Wlds[(c4 * 4 + 0) * 64 + o] = w.x;
                Wlds[(c4 * 4 + 1) * 64 + o] = w.y;
                Wlds[(c4 * 4 + 2) * 64 + o] = w.z;
                Wlds[(c4 * 4 + 3) * 64 + o] = w.w;
            }
            __syncthreads();
#pragma unroll 8
            for (int k = 0; k < 32; ++k) {
                float4 a0 = *(const float4*)(Slds + k * 128 + tb);
                float4 a1 = *(const float4*)(Slds + k * 128 + 64 + tb);
                float4 b0 = *(const float4*)(Wlds + k * 64 + ob);
                float4 b1 = *(const float4*)(Wlds + k * 64 + 32 + ob);
                float a[8]  = {a0.x, a0.y, a0.z, a0.w, a1.x, a1.y, a1.z, a1.w};
                float bv[8] = {b0.x, b0.y, b0.z, b0.w, b1.x, b1.y, b1.z, b1.w};
#pragma unroll
                for (int ii = 0; ii < 8; ++ii)
#pragma unroll
                    for (int jj = 0; jj < 8; ++jj)
                        acc[ii][jj] += a[ii] * bv[jj];
            }
            __syncthreads();
        }

#pragma unroll
        for (int ii = 0; ii < 8; ++ii) {
            int t = (ii >> 2) * 64 + tb + (ii & 3);
#pragma unroll
            for (int os = 0; os < 2; ++os) {
                float4 v = make_float4(acc[ii][os * 4 + 0], acc[ii][os * 4 + 1],
                                       acc[ii][os * 4 + 2], acc[ii][os * 4 + 3]);
                *(float4*)(Mlds + t * 68 + os * 32 + ob) = v;
            }
        }
        __syncthreads();

        if (tid < 64) {
#pragma unroll 4
            for (int t = 0; t < 128; ++t) {
                float x = Mlds[t * 68 + tid];
                mem = 0.9f * mem + x - spk * 0.75f;
                spk = (mem > 0.75f) ? 1.0f : 0.0f;
                cnt += spk;
                Mlds[t * 68 + tid] = spk;
            }
        }
        __syncthreads();

        if (isRx) {
            float* dst = out + (size_t)OUT_RX + (size_t)(g - 64) * C_ * T_
                         + (size_t)o0 * T_ + t0;
            int m = tid & 7;
            int orow0 = tid >> 3;
#pragma unroll
            for (int p = 0; p < 4; ++p) {
                int orow = orow0 + p * 16;
#pragma unroll
                for (int q = 0; q < 4; ++q) {
                    int tq = m * 4 + q * 32;
                    float4 v = make_float4(Mlds[(tq + 0) * 68 + orow],
                                           Mlds[(tq + 1) * 68 + orow],
                                           Mlds[(tq + 2) * 68 + orow],
                                           Mlds[(tq + 3) * 68 + orow]);
                    *(float4*)(dst + (size_t)orow * T_ + tq) = v;
                }
            }
        }
        __syncthreads();
    }

    if (tid < 64) {
        if (isRx) out[(size_t)OUT_SP + (size_t)(g - 64) * C_ + o0 + tid] = cnt;
        else      wsF[(size_t)g * C_ + o0 + tid] = cnt;
    }
}

// Heads: layernorm over C=256 + GEMV to H=512, 3 heads x 64 batches
__global__ __launch_bounds__(256) void heads_kernel(
    const float* __restrict__ wsF, const float* __restrict__ sp,
    const float* __restrict__ Wd, const float* __restrict__ bd,
    const float* __restrict__ Wa, const float* __restrict__ ba,
    const float* __restrict__ We, const float* __restrict__ be,
    const float* __restrict__ gd, const float* __restrict__ ga, const float* __restrict__ ge,
    const float* __restrict__ based, const float* __restrict__ basea, const float* __restrict__ basee,
    float* __restrict__ out)
{
    __shared__ float fv[256];
    __shared__ float red[8];
    const int tid = threadIdx.x;
    const int hd  = blockIdx.x >> 6;
    const int b   = blockIdx.x & 63;

    float f;
    if (hd == 0) {
        f = wsF[b * 256 + tid] * (1.f / 1024.f);
    } else {
        float l = sp[(2 * b) * 256 + tid];
        float r = sp[(2 * b + 1) * 256 + tid];
        f = ((hd == 1) ? (l - r) : (l + r)) * (1.f / 1024.f);
    }

    float v = f;
#pragma unroll
    for (int off = 32; off > 0; off >>= 1) v += __shfl_down(v, off, 64);
    if ((tid & 63) == 0) red[tid >> 6] = v;
    __syncthreads();
    float mu = (red[0] + red[1] + red[2] + red[3]) * (1.f / 256.f);

    float d = f - mu;
    v = d * d;
#pragma unroll
    for (int off = 32; off > 0; off >>= 1) v += __shfl_down(v, off, 64);
    if ((tid & 63) == 0) red[4 + (tid >> 6)] = v;
    __syncthreads();
    float var  = (red[4] + red[5] + red[6] + red[7]) * (1.f / 256.f);
    float rstd = rsqrtf(var + 1e-5f);
    fv[tid] = d * rstd;
    __syncthreads();

    const float* W    = (hd == 0) ? Wd : (hd == 1) ? Wa : We;
    const float* bb   = (hd == 0) ? bd : (hd == 1) ? ba : be;
    const float* base = (hd == 0) ? based : (hd == 1) ? basea : basee;
    float gain = (hd == 0) ? gd[0] : (hd == 1) ? ga[0] : ge[0];
    float s = 0.3f / (1.f + expf(-gain));

    const float4* fv4 = (const float4*)fv;
#pragma unroll
    for (int hh = 0; hh < 2; ++hh) {
        int h = tid + hh * 256;
        const float4* W4 = (const float4*)(W + (size_t)h * 256);
        float acc = 0.f;
#pragma unroll 8
        for (int c = 0; c < 64; ++c) {
            float4 w = W4[c];
            float4 x = fv4[c];
            acc += w.x * x.x + w.y * x.y + w.z * x.z + w.w * x.w;
        }
        float r = acc + bb[h];
        float o = base[b * 512 + h] + s * r;
        out[(size_t)hd * (64 * 512) + b * 512 + h] = fmaxf(o, 0.f);
    }
}

extern "C" void kernel_launch(void* const* d_in, const int* in_sizes, int n_in,
                              void* d_out, int out_size, void* d_ws, size_t ws_size,
                              hipStream_t stream)
{
    const float* transmit = (const float*)d_in[0];
    const float* receive  = (const float*)d_in[1];
    const float* based    = (const float*)d_in[2];
    const float* basea    = (const float*)d_in[3];
    const float* basee    = (const float*)d_in[4];
    const float* Wtx      = (const float*)d_in[5];
    const float* btx      = (const float*)d_in[6];
    const float* Wrx      = (const float*)d_in[7];
    const float* brx      = (const float*)d_in[8];
    const float* Wd       = (const float*)d_in[9];
    const float* bd       = (const float*)d_in[10];
    const float* Wa       = (const float*)d_in[11];
    const float* ba       = (const float*)d_in[12];
    const float* We       = (const float*)d_in[13];
    const float* be       = (const float*)d_in[14];
    const float* gd       = (const float*)d_in[15];
    const float* ga       = (const float*)d_in[16];
    const float* ge       = (const float*)d_in[17];
    float* out = (float*)d_out;
    float* spOut = out + (size_t)OUT_SP;

    const size_t need = 512 * 1024 + 64 * 1024;   // W16 splits + tx counts

    if (ws_size >= need) {
        _Float16* w16   = (_Float16*)d_ws;
        float*    txCnt = (float*)d_ws + 131072;  // after 512 KB

        hipLaunchKernelGGL(split_w, dim3(512), dim3(256), 0, stream,
                           Wtx, Wrx, w16);
        hipLaunchKernelGGL(lif_mfma_v4, dim3(768), dim3(256), 0, stream,
                           transmit, receive, btx, brx, w16, out, txCnt);
        hipLaunchKernelGGL(heads_kernel, dim3(192), dim3(256), 0, stream,
                           txCnt, spOut, Wd, bd, Wa, ba, We, be,
                           gd, ga, ge, based, basea, basee, out);
    } else {
        float* wsF = (float*)d_ws;
        hipLaunchKernelGGL(lif_gemm_scan, dim3(768), dim3(128), 0, stream,
                           transmit, receive, Wtx, btx, Wrx, brx, out, wsF);
        hipLaunchKernelGGL(heads_kernel, dim3(192), dim3(256), 0, stream,
                           wsF, spOut, Wd, bd, Wa, ba, We, be,
                           gd, ga, ge, based, basea, basee, out);
    }
}